// Round 4
// baseline (149.312 us; speedup 1.0000x reference)
//
#include <hip/hip_runtime.h>
#include <math.h>
#include <stdint.h>

// NetVLAD: N=32, C=512, P=1024, K=64, ALPHA=100. Split-bf16 MFMA,
// barrier-free per-wave K-loops (no __syncthreads -> no vmcnt(0) drain).
#define ALPHA 100.0f
#define EPSN 1e-12f

typedef __attribute__((ext_vector_type(8))) short bf16x8;    // 8 bf16 = 4 VGPR
typedef __attribute__((ext_vector_type(16))) float f32x16;   // 32x32 acc
typedef __attribute__((ext_vector_type(4))) unsigned int u32x4;

static __device__ __forceinline__ uint32_t f2bf(float f) {
    uint32_t u = __builtin_bit_cast(uint32_t, f);
    return (u + 0x7FFFu + ((u >> 16) & 1u)) >> 16;  // RNE
}
static __device__ __forceinline__ float bfhi(uint32_t u) {  // hi bf16 as f32
    return __builtin_bit_cast(float, u & 0xFFFF0000u);
}
static __device__ __forceinline__ float bflo(uint32_t u) {  // lo bf16 as f32
    return __builtin_bit_cast(float, u << 16);
}
// one element -> packed (hi<<16)|lo split-bf16
static __device__ __forceinline__ uint32_t stage1(float f) {
    uint32_t hi = f2bf(f);
    uint32_t lo = f2bf(f - __builtin_bit_cast(float, hi << 16));
    return (hi << 16) | lo;
}
static __device__ __forceinline__ uint32_t packbf(float a, float b) {
    return f2bf(a) | (f2bf(b) << 16);
}

// ---------------- prep: v -> (vh, vl) bf16 split [k][c]; bias[k] ------------
__global__ __launch_bounds__(64) void prep_kernel(const float* __restrict__ v,
                                                  unsigned short* __restrict__ vh,
                                                  unsigned short* __restrict__ vl,
                                                  float* __restrict__ bias) {
    int k = blockIdx.x, lane = threadIdx.x;
    const float* row = v + k * 512;
    float ssq = 0.f;
#pragma unroll
    for (int i = 0; i < 8; ++i) {
        int c = lane + 64 * i;
        float f = row[c];
        ssq = fmaf(f, f, ssq);
        uint32_t hi = f2bf(f);
        uint32_t lo = f2bf(f - __builtin_bit_cast(float, hi << 16));
        vh[k * 512 + c] = (unsigned short)hi;
        vl[k * 512 + c] = (unsigned short)lo;
    }
#pragma unroll
    for (int off = 32; off > 0; off >>= 1) ssq += __shfl_xor(ssq, off, 64);
    if (lane == 0) bias[k] = -ALPHA * sqrtf(ssq);
}

// ================= P1 assign: D[k][p] = sum_c v[k][c]*x[c][p] ===============
// grid 256 = (n, 128-p block); block 256 = 4 waves; wave: 64k x 32p, private
// LDS slab [32c][32p] packed split-bf16. v gathered global->reg (L1/L2-hot).
static __device__ __forceinline__ void assign_body(
    int i, float4 (&pxc)[4], u32x4 (&qvc)[8], u32x4 (&qvn)[8],
    f32x16& acc0, f32x16& acc1, float& ssq, uint32_t* xwp,
    const float* xg, const unsigned short* vhr0, const unsigned short* vhr1,
    const unsigned short* vlr0, const unsigned short* vlr1,
    int crow, int p4, int h, int cl) {
    // stage chunk i (consume pxc)
#pragma unroll
    for (int k = 0; k < 4; ++k) {
        float4 v = pxc[k];
        int idx = (8 * k + crow) * 34 + p4;
        *(uint2*)&xwp[idx] = make_uint2(stage1(v.x), stage1(v.y));
        *(uint2*)&xwp[idx + 2] = make_uint2(stage1(v.z), stage1(v.w));
    }
    // prefetch x chunk i+2 into pxc (wrap: redundant-but-valid at tail)
    int cpre = ((i + 2) & 15) * 32;
#pragma unroll
    for (int k = 0; k < 4; ++k)
        pxc[k] = *(const float4*)(xg + (size_t)(cpre + 8 * k + crow) * 1024 + p4);
    // prefetch v chunk i+1 into qvn
    int co = ((i + 1) & 15) * 32 + 8 * h;
    qvn[0] = *(const u32x4*)(vhr0 + co);
    qvn[1] = *(const u32x4*)(vhr1 + co);
    qvn[2] = *(const u32x4*)(vlr0 + co);
    qvn[3] = *(const u32x4*)(vlr1 + co);
    qvn[4] = *(const u32x4*)(vhr0 + co + 16);
    qvn[5] = *(const u32x4*)(vhr1 + co + 16);
    qvn[6] = *(const u32x4*)(vlr0 + co + 16);
    qvn[7] = *(const u32x4*)(vlr1 + co + 16);
    // gather B-frags from own slab + 3-pass MFMA
#pragma unroll
    for (int s = 0; s < 2; ++s) {
        bf16x8 ah0 = __builtin_bit_cast(bf16x8, qvc[4 * s + 0]);
        bf16x8 ah1 = __builtin_bit_cast(bf16x8, qvc[4 * s + 1]);
        bf16x8 al0 = __builtin_bit_cast(bf16x8, qvc[4 * s + 2]);
        bf16x8 al1 = __builtin_bit_cast(bf16x8, qvc[4 * s + 3]);
        uint32_t wv[8];
#pragma unroll
        for (int j = 0; j < 8; ++j)
            wv[j] = xwp[(16 * s + 8 * h + j) * 34 + cl];
#pragma unroll
        for (int j = 0; j < 8; ++j) {
            float xr = bfhi(wv[j]) + bflo(wv[j]);
            ssq = fmaf(xr, xr, ssq);
        }
        u32x4 bhp, blp;
#pragma unroll
        for (int q = 0; q < 4; ++q) {
            bhp[q] = (wv[2 * q] >> 16) | (wv[2 * q + 1] & 0xFFFF0000u);
            blp[q] = (wv[2 * q] & 0xFFFFu) | (wv[2 * q + 1] << 16);
        }
        bf16x8 bh = __builtin_bit_cast(bf16x8, bhp);
        bf16x8 bl = __builtin_bit_cast(bf16x8, blp);
        acc0 = __builtin_amdgcn_mfma_f32_32x32x16_bf16(ah0, bh, acc0, 0, 0, 0);
        acc1 = __builtin_amdgcn_mfma_f32_32x32x16_bf16(ah1, bh, acc1, 0, 0, 0);
        acc0 = __builtin_amdgcn_mfma_f32_32x32x16_bf16(ah0, bl, acc0, 0, 0, 0);
        acc1 = __builtin_amdgcn_mfma_f32_32x32x16_bf16(ah1, bl, acc1, 0, 0, 0);
        acc0 = __builtin_amdgcn_mfma_f32_32x32x16_bf16(al0, bh, acc0, 0, 0, 0);
        acc1 = __builtin_amdgcn_mfma_f32_32x32x16_bf16(al1, bh, acc1, 0, 0, 0);
    }
}

__global__ __launch_bounds__(256) void assign_kernel(
    const float* __restrict__ x, const unsigned short* __restrict__ vh,
    const unsigned short* __restrict__ vl, const float* __restrict__ bias,
    unsigned short* __restrict__ aT, float* __restrict__ asum,
    float* __restrict__ sinv_g) {
    __shared__ uint32_t xw[4][32 * 34];  // per-wave packed split-bf16 [c][p]
    __shared__ float bias_l[64];
    int tid = threadIdx.x, bx = blockIdx.x;
    int n = bx >> 3, pblk = (bx & 7) << 7;
    int l = tid & 63, w = tid >> 6, h = l >> 5, cl = l & 31;
    if (tid < 64) bias_l[tid] = bias[tid];
    const float* xg = x + (size_t)n * 524288 + pblk + 32 * w;
    int crow = l >> 3, p4 = (l & 7) << 2;
    const unsigned short* vhr0 = vh + cl * 512;
    const unsigned short* vhr1 = vh + (cl + 32) * 512;
    const unsigned short* vlr0 = vl + cl * 512;
    const unsigned short* vlr1 = vl + (cl + 32) * 512;
    uint32_t* xwp = xw[w];

    f32x16 acc0, acc1;
#pragma unroll
    for (int r = 0; r < 16; ++r) { acc0[r] = 0.f; acc1[r] = 0.f; }
    float ssq = 0.f;

    float4 px0[4], px1[4];
    u32x4 qv0[8], qv1[8];
#pragma unroll
    for (int k = 0; k < 4; ++k) {
        px0[k] = *(const float4*)(xg + (size_t)(8 * k + crow) * 1024 + p4);
        px1[k] = *(const float4*)(xg + (size_t)(32 + 8 * k + crow) * 1024 + p4);
    }
    {
        int co = 8 * h;
        qv0[0] = *(const u32x4*)(vhr0 + co);
        qv0[1] = *(const u32x4*)(vhr1 + co);
        qv0[2] = *(const u32x4*)(vlr0 + co);
        qv0[3] = *(const u32x4*)(vlr1 + co);
        qv0[4] = *(const u32x4*)(vhr0 + co + 16);
        qv0[5] = *(const u32x4*)(vhr1 + co + 16);
        qv0[6] = *(const u32x4*)(vlr0 + co + 16);
        qv0[7] = *(const u32x4*)(vlr1 + co + 16);
    }
    for (int ii = 0; ii < 16; ii += 2) {
        assign_body(ii, px0, qv0, qv1, acc0, acc1, ssq, xwp, xg,
                    vhr0, vhr1, vlr0, vlr1, crow, p4, h, cl);
        assign_body(ii + 1, px1, qv1, qv0, acc0, acc1, ssq, xwp, xg,
                    vhr0, vhr1, vlr0, vlr1, crow, p4, h, cl);
    }
    __syncthreads();  // bias_l visibility (only barrier in kernel)

    // epilogue: softmax over 64 k (32 in-lane + shfl_xor 32)
    float ssqv = ssq + __shfl_xor(ssq, 32, 64);
    float sv = 1.0f / fmaxf(sqrtf(ssqv), EPSN);
    int p_l = 32 * w + cl;
    if (h == 0) sinv_g[n * 1024 + pblk + p_l] = sv;
    float twoAs = 2.0f * ALPHA * sv;
    float e[2][16];
    float m = -INFINITY;
#pragma unroll
    for (int t = 0; t < 2; ++t)
#pragma unroll
        for (int r = 0; r < 16; ++r) {
            int k = (r & 3) + 8 * (r >> 2) + 4 * h + 32 * t;
            float lv = fmaf(twoAs, (t ? acc1[r] : acc0[r]), bias_l[k]);
            e[t][r] = lv;
            m = fmaxf(m, lv);
        }
    m = fmaxf(m, __shfl_xor(m, 32, 64));
    float s = 0.f;
#pragma unroll
    for (int t = 0; t < 2; ++t)
#pragma unroll
        for (int r = 0; r < 16; ++r) {
            e[t][r] = expf(e[t][r] - m);
            s += e[t][r];
        }
    s += __shfl_xor(s, 32, 64);
    float rs = 1.0f / s;
    unsigned short* aTn = aT + (size_t)n * 65536 + pblk + p_l;
#pragma unroll
    for (int t = 0; t < 2; ++t)
#pragma unroll
        for (int r = 0; r < 16; ++r) {
            int k = (r & 3) + 8 * (r >> 2) + 4 * h + 32 * t;
            float a = e[t][r] * rs;
            aTn[(size_t)k * 1024] = (unsigned short)f2bf(a);
            float red = a;
#pragma unroll
            for (int off = 1; off <= 16; off <<= 1) red += __shfl_xor(red, off, 64);
            if (cl == 0) atomicAdd(&asum[n * 64 + k], red);
        }
}

// ================= P2 vlad: D[k][c] = sum_p aT[k][p]*xhat[c][p] =============
// grid 256 XCD-swizzled (same-n blocks share an XCD's L2 for aT); block 256 =
// 4 waves (wk,wc); per-wave private x-hat slab [32c][64p] bf16 pairs; aT
// gathered global->reg. No barriers in K-loop.
static __device__ __forceinline__ void vlad_body(
    int i, float4 (&qxc)[8], u32x4 (&qac)[4], u32x4 (&qan)[4], f32x16& acc,
    uint32_t* xwp, const float* xg, const unsigned short* ag,
    const float* sinv_l, int crow, int p16, int h, int cl) {
    int p0 = i << 6;
    float4 sv4 = *(const float4*)&sinv_l[p0 + p16];
#pragma unroll
    for (int k = 0; k < 8; ++k) {
        float4 v = qxc[k];
        int idx = (4 * k + crow) * 34 + (p16 >> 1);
        *(uint2*)&xwp[idx] = make_uint2(packbf(v.x * sv4.x, v.y * sv4.y),
                                        packbf(v.z * sv4.z, v.w * sv4.w));
    }
    int ppre = ((i + 2) & 15) << 6;
#pragma unroll
    for (int k = 0; k < 8; ++k)
        qxc[k] = *(const float4*)(xg + (size_t)(4 * k + crow) * 1024 + ppre + p16);
    int pnext = ((i + 1) & 15) << 6;
#pragma unroll
    for (int s = 0; s < 4; ++s)
        qan[s] = *(const u32x4*)(ag + pnext + 16 * s);
#pragma unroll
    for (int s = 0; s < 4; ++s) {
        bf16x8 af = __builtin_bit_cast(bf16x8, qac[s]);
        uint2 r0 = *(const uint2*)&xwp[cl * 34 + 8 * s + 4 * h];
        uint2 r1 = *(const uint2*)&xwp[cl * 34 + 8 * s + 4 * h + 2];
        u32x4 bb;
        bb[0] = r0.x; bb[1] = r0.y; bb[2] = r1.x; bb[3] = r1.y;
        acc = __builtin_amdgcn_mfma_f32_32x32x16_bf16(
            af, __builtin_bit_cast(bf16x8, bb), acc, 0, 0, 0);
    }
}

__global__ __launch_bounds__(256) void vlad_kernel(
    const float* __restrict__ x, const unsigned short* __restrict__ aT,
    const float* __restrict__ sinv_g, const float* __restrict__ asum,
    const float* __restrict__ vocabs, float* __restrict__ out,
    float* __restrict__ knorm) {
    __shared__ uint32_t xw[4][32 * 34];  // per-wave xhat bf16 pairs [c][p2]
    __shared__ float sinv_l[1024];
    __shared__ float asum_l[64];
    int tid = threadIdx.x, bx = blockIdx.x;
    int n = (bx & 7) * 4 + (bx >> 6);        // XCD swizzle: 8 c-blocks of one
    int cblk = ((bx >> 3) & 7) << 6;         // n land on one XCD (bx%8 const)
    int l = tid & 63, w = tid >> 6, h = l >> 5, cl = l & 31;
    int wk = w & 1, wc = w >> 1;
    ((float4*)sinv_l)[tid] = ((const float4*)(sinv_g + n * 1024))[tid];
    if (tid < 64) asum_l[tid] = asum[n * 64 + tid];
    __syncthreads();  // sinv_l/asum_l ready (only barrier; before prologue)

    const float* xg = x + (size_t)n * 524288 + (size_t)(cblk + 32 * wc) * 1024;
    const unsigned short* ag = aT + (size_t)n * 65536 + (32 * wk + cl) * 1024 + 8 * h;
    int crow = l >> 4, p16 = (l & 15) << 2;
    uint32_t* xwp = xw[w];

    f32x16 acc;
#pragma unroll
    for (int r = 0; r < 16; ++r) acc[r] = 0.f;

    float4 qx0[8], qx1[8];
    u32x4 qa0[4], qa1[4];
#pragma unroll
    for (int k = 0; k < 8; ++k) {
        qx0[k] = *(const float4*)(xg + (size_t)(4 * k + crow) * 1024 + p16);
        qx1[k] = *(const float4*)(xg + (size_t)(4 * k + crow) * 1024 + 64 + p16);
    }
#pragma unroll
    for (int s = 0; s < 4; ++s) qa0[s] = *(const u32x4*)(ag + 16 * s);

    for (int ii = 0; ii < 16; ii += 2) {
        vlad_body(ii, qx0, qa0, qa1, acc, xwp, xg, ag, sinv_l, crow, p16, h, cl);
        vlad_body(ii + 1, qx1, qa1, qa0, acc, xwp, xg, ag, sinv_l, crow, p16, h, cl);
    }
    // epilogue: -asum*v, store raw, knorm atomics
#pragma unroll
    for (int r = 0; r < 16; ++r) {
        int k = (r & 3) + 8 * (r >> 2) + 4 * h + 32 * wk;
        int c = cblk + 32 * wc + cl;
        float val = fmaf(-asum_l[k], vocabs[k * 512 + c], acc[r]);
        out[(size_t)n * 32768 + (size_t)k * 512 + c] = val;
        float t2 = val * val;
#pragma unroll
        for (int off = 1; off <= 16; off <<= 1) t2 += __shfl_xor(t2, off, 64);
        if (cl == 0) atomicAdd(&knorm[n * 64 + k], t2);
    }
}

// ---------------- scale: intra-norm (per k) * global norm (per n), in place -
__global__ __launch_bounds__(256) void scale_kernel(float* __restrict__ out,
                                                    const float* __restrict__ knorm) {
    int n = blockIdx.y;
    int sb = blockIdx.x;
    int tid = threadIdx.x;
    __shared__ float sc[64];
    __shared__ float tots;
    if (tid < 64) {
        float kn = knorm[n * 64 + tid];
        float nk = sqrtf(kn);
        float inv = 1.0f / fmaxf(nk, EPSN);
        sc[tid] = inv;
        float t = nk * inv;
        float t2 = t * t;
#pragma unroll
        for (int off = 32; off > 0; off >>= 1) t2 += __shfl_xor(t2, off, 64);
        if (tid == 0) tots = t2;
    }
    __syncthreads();
    float invt = 1.0f / fmaxf(sqrtf(tots), EPSN);
    float* base = out + (size_t)n * 32768 + sb * 4096;
#pragma unroll
    for (int i = 0; i < 16; ++i) {
        int idx = tid + 256 * i;
        int k = (sb * 4096 + idx) >> 9;
        base[idx] *= sc[k] * invt;
    }
}

extern "C" void kernel_launch(void* const* d_in, const int* in_sizes, int n_in,
                              void* d_out, int out_size, void* d_ws, size_t ws_size,
                              hipStream_t stream) {
    const float* x = (const float*)d_in[0];       // [32,512,32,32]
    const float* vocabs = (const float*)d_in[1];  // [64,512]
    float* out = (float*)d_out;                   // [32, 32768]
    char* ws = (char*)d_ws;
    unsigned short* vh = (unsigned short*)(ws);            // 65536 B
    unsigned short* vl = (unsigned short*)(ws + 65536);    // 65536 B
    float* bias  = (float*)(ws + 131072);                  //   256 B
    float* asum  = (float*)(ws + 131328);                  //  8192 B (memset)
    float* knorm = (float*)(ws + 139520);                  //  8192 B (memset)
    float* sinv  = (float*)(ws + 147712);                  // 131072 B
    unsigned short* aT = (unsigned short*)(ws + 278784);   // 4 MB [n][k][p]

    hipMemsetAsync(asum, 0, 16384, stream);  // asum + knorm contiguous
    prep_kernel<<<64, 64, 0, stream>>>(vocabs, vh, vl, bias);
    assign_kernel<<<256, 256, 0, stream>>>(x, vh, vl, bias, aT, asum, sinv);
    vlad_kernel<<<256, 256, 0, stream>>>(x, aT, sinv, asum, vocabs, out, knorm);
    scale_kernel<<<dim3(8, 32), 256, 0, stream>>>(out, knorm);
}

// Round 5
// 139.687 us; speedup vs baseline: 1.0689x; 1.0689x over previous
//
#include <hip/hip_runtime.h>
#include <math.h>
#include <stdint.h>

// NetVLAD: N=32, C=512, P=1024, K=64, ALPHA=100. Split-bf16 MFMA.
// R5: 32k x 32p wave tiles -> 8 waves/CU, 2 blocks/CU; coop coalesced
// staging (2-barrier m97 loop); a2 = a*sinv so vlad is a pure bf16 GEMM.
#define ALPHA 100.0f
#define EPSN 1e-12f

typedef __attribute__((ext_vector_type(8))) short bf16x8;
typedef __attribute__((ext_vector_type(16))) float f32x16;
typedef __attribute__((ext_vector_type(4))) unsigned int u32x4;

static __device__ __forceinline__ uint32_t f2bf(float f) {
    uint32_t u = __builtin_bit_cast(uint32_t, f);
    return (u + 0x7FFFu + ((u >> 16) & 1u)) >> 16;  // RNE
}
static __device__ __forceinline__ float bfhi(uint32_t u) {
    return __builtin_bit_cast(float, u & 0xFFFF0000u);
}
static __device__ __forceinline__ float bflo(uint32_t u) {
    return __builtin_bit_cast(float, u << 16);
}
static __device__ __forceinline__ uint32_t stage1(float f) {  // (hi<<16)|lo split
    uint32_t hi = f2bf(f);
    uint32_t lo = f2bf(f - __builtin_bit_cast(float, hi << 16));
    return (hi << 16) | lo;
}
static __device__ __forceinline__ uint32_t packbf(float a, float b) {
    return f2bf(a) | (f2bf(b) << 16);
}

// ------- prep: v -> (vh, vl) bf16 split [k][c]; bias[k]; zero asum/knorm ----
__global__ __launch_bounds__(64) void prep_kernel(const float* __restrict__ v,
                                                  unsigned short* __restrict__ vh,
                                                  unsigned short* __restrict__ vl,
                                                  float* __restrict__ bias,
                                                  float* __restrict__ az) {
    int k = blockIdx.x, lane = threadIdx.x;
    az[k * 64 + lane] = 0.f;  // 4096 floats = asum(2048)+knorm(2048)
    const float* row = v + k * 512;
    float ssq = 0.f;
#pragma unroll
    for (int i = 0; i < 8; ++i) {
        int c = lane + 64 * i;
        float f = row[c];
        ssq = fmaf(f, f, ssq);
        uint32_t hi = f2bf(f);
        uint32_t lo = f2bf(f - __builtin_bit_cast(float, hi << 16));
        vh[k * 512 + c] = (unsigned short)hi;
        vl[k * 512 + c] = (unsigned short)lo;
    }
#pragma unroll
    for (int off = 32; off > 0; off >>= 1) ssq += __shfl_xor(ssq, off, 64);
    if (lane == 0) bias[k] = -ALPHA * sqrtf(ssq);
}

// ================= P1 assign: D[k][p] = sum_c v[k][c]*x[c][p] ===============
// grid 512 = (n, 64-p block); block 256 = 4 waves (kh,ph), wave 32k x 32p.
// K-loop: 16 chunks of 32c; coop staging; 3-pass split-bf16 MFMA.
// Epilogue: softmax (cross-kh LDS exchange), aT = bf16(a*sinv), asum atomics.
__global__ __launch_bounds__(256) void assign_kernel(
    const float* __restrict__ x, const unsigned short* __restrict__ vh,
    const unsigned short* __restrict__ vl, const float* __restrict__ bias,
    unsigned short* __restrict__ aT, float* __restrict__ asum) {
    __shared__ uint32_t xs[32 * 66];   // packed split x [32c][64p], pitch 66
    __shared__ uint32_t vhs[64 * 18];  // vh [64k][16 u32], pitch 18 (2-way ok)
    __shared__ uint32_t vls[64 * 18];
    __shared__ float bias_l[64];
    __shared__ float xch[2][2][32];    // cross-kh softmax exchange

    int tid = threadIdx.x, bx = blockIdx.x;
    int n = bx >> 4, pblk = (bx & 15) << 6;
    int l = tid & 63, w = tid >> 6;
    int kh = w & 1, ph = w >> 1;       // wave tile: k in [32kh,..), p in [32ph,..)
    int h = l >> 5, cl = l & 31;

    if (tid < 64) bias_l[tid] = bias[tid];

    int xr = tid >> 4;                 // c rows xr, xr+16 (16 thr/row: 256B)
    int xq = (tid & 15) << 2;          // p quad
    int vk = tid >> 2;                 // k row (4 thr/row: 64B)
    int vj = (tid & 3) << 3;           // short col 0,8,16,24

    const float* xg = x + (size_t)n * 524288 + pblk;
    const unsigned short* vhg = vh + vk * 512 + vj;
    const unsigned short* vlg = vl + vk * 512 + vj;

    f32x16 acc;
#pragma unroll
    for (int r = 0; r < 16; ++r) acc[r] = 0.f;
    float ssq = 0.f;

    float4 pxa = *(const float4*)(xg + (size_t)xr * 1024 + xq);
    float4 pxb = *(const float4*)(xg + (size_t)(xr + 16) * 1024 + xq);
    u32x4 pvh = *(const u32x4*)vhg;
    u32x4 pvl = *(const u32x4*)vlg;

    for (int ch = 0; ch < 16; ++ch) {
        __syncthreads();  // LDS free (prev readers done)
        *(uint2*)&xs[xr * 66 + xq] = make_uint2(stage1(pxa.x), stage1(pxa.y));
        *(uint2*)&xs[xr * 66 + xq + 2] = make_uint2(stage1(pxa.z), stage1(pxa.w));
        *(uint2*)&xs[(xr + 16) * 66 + xq] = make_uint2(stage1(pxb.x), stage1(pxb.y));
        *(uint2*)&xs[(xr + 16) * 66 + xq + 2] = make_uint2(stage1(pxb.z), stage1(pxb.w));
        int vb = vk * 18 + (vj >> 1);
        *(uint2*)&vhs[vb] = make_uint2(pvh[0], pvh[1]);
        *(uint2*)&vhs[vb + 2] = make_uint2(pvh[2], pvh[3]);
        *(uint2*)&vls[vb] = make_uint2(pvl[0], pvl[1]);
        *(uint2*)&vls[vb + 2] = make_uint2(pvl[2], pvl[3]);
        __syncthreads();  // tiles ready
        if (ch < 15) {    // prefetch next chunk (in flight during compute)
            int c0 = (ch + 1) << 5;
            pxa = *(const float4*)(xg + (size_t)(c0 + xr) * 1024 + xq);
            pxb = *(const float4*)(xg + (size_t)(c0 + xr + 16) * 1024 + xq);
            pvh = *(const u32x4*)(vhg + c0);
            pvl = *(const u32x4*)(vlg + c0);
        }
#pragma unroll
        for (int s = 0; s < 2; ++s) {
            int va = (32 * kh + cl) * 18 + 8 * s + 4 * h;
            uint2 a0 = *(const uint2*)&vhs[va];
            uint2 a1 = *(const uint2*)&vhs[va + 2];
            uint2 b0 = *(const uint2*)&vls[va];
            uint2 b1 = *(const uint2*)&vls[va + 2];
            u32x4 ahp, alp;
            ahp[0] = a0.x; ahp[1] = a0.y; ahp[2] = a1.x; ahp[3] = a1.y;
            alp[0] = b0.x; alp[1] = b0.y; alp[2] = b1.x; alp[3] = b1.y;
            uint32_t wv[8];
#pragma unroll
            for (int j = 0; j < 8; ++j)
                wv[j] = xs[(16 * s + 8 * h + j) * 66 + 32 * ph + cl];
#pragma unroll
            for (int j = 0; j < 8; ++j) {
                float xv = bfhi(wv[j]) + bflo(wv[j]);
                ssq = fmaf(xv, xv, ssq);
            }
            u32x4 bhp, blp;
#pragma unroll
            for (int q = 0; q < 4; ++q) {
                bhp[q] = (wv[2 * q] >> 16) | (wv[2 * q + 1] & 0xFFFF0000u);
                blp[q] = (wv[2 * q] & 0xFFFFu) | (wv[2 * q + 1] << 16);
            }
            bf16x8 ah = __builtin_bit_cast(bf16x8, ahp);
            bf16x8 al = __builtin_bit_cast(bf16x8, alp);
            bf16x8 bh = __builtin_bit_cast(bf16x8, bhp);
            bf16x8 bl = __builtin_bit_cast(bf16x8, blp);
            acc = __builtin_amdgcn_mfma_f32_32x32x16_bf16(ah, bh, acc, 0, 0, 0);
            acc = __builtin_amdgcn_mfma_f32_32x32x16_bf16(ah, bl, acc, 0, 0, 0);
            acc = __builtin_amdgcn_mfma_f32_32x32x16_bf16(al, bh, acc, 0, 0, 0);
        }
    }
    // ---- epilogue: softmax over 64 k for each p-col ----
    ssq += __shfl_xor(ssq, 32, 64);           // both c-halves
    float sinv = 1.0f / fmaxf(sqrtf(ssq), EPSN);
    float twoAs = 2.0f * ALPHA * sinv;
    float e[16];
    float m = -INFINITY;
#pragma unroll
    for (int r = 0; r < 16; ++r) {
        int k = (r & 3) + 8 * (r >> 2) + 4 * h + 32 * kh;
        float lv = fmaf(twoAs, acc[r], bias_l[k]);
        e[r] = lv;
        m = fmaxf(m, lv);
    }
    m = fmaxf(m, __shfl_xor(m, 32, 64));      // own-wave 32k max
    __syncthreads();
    if (l < 32) xch[kh][ph][l] = m;
    __syncthreads();
    m = fmaxf(m, xch[1 - kh][ph][cl]);        // full 64k max
    float ssum = 0.f;
#pragma unroll
    for (int r = 0; r < 16; ++r) {
        e[r] = expf(e[r] - m);
        ssum += e[r];
    }
    ssum += __shfl_xor(ssum, 32, 64);
    __syncthreads();
    if (l < 32) xch[kh][ph][l] = ssum;
    __syncthreads();
    ssum += xch[1 - kh][ph][cl];
    float rs = 1.0f / ssum;
    float a2s = rs * sinv;                    // a2 = a*sinv (scale on a-side)
    unsigned short* aTn = aT + (size_t)n * 65536 + pblk + 32 * ph + cl;
#pragma unroll
    for (int r = 0; r < 16; ++r) {
        int k = (r & 3) + 8 * (r >> 2) + 4 * h + 32 * kh;
        aTn[(size_t)k * 1024] = (unsigned short)f2bf(e[r] * a2s);
        float red = e[r] * rs;                // plain a for asum
#pragma unroll
        for (int off = 1; off <= 16; off <<= 1) red += __shfl_xor(red, off, 64);
        if (cl == 0) atomicAdd(&asum[n * 64 + k], red);
    }
}

// ================= P2 vlad: D[k][c] = sum_p a2[k][p]*bf16(x)[c][p] ==========
// Pure bf16 GEMM (sinv folded into a2). grid 512 = (n, 32-c block); block 256
// = 4 waves (kh, p-parity). x re-read from L3 (assign just streamed it).
__global__ __launch_bounds__(256) void vlad_kernel(
    const float* __restrict__ x, const unsigned short* __restrict__ aT,
    const float* __restrict__ asum, const float* __restrict__ vocabs,
    float* __restrict__ out, float* __restrict__ knorm) {
    __shared__ uint32_t xt[32 * 34];   // bf16 pairs [32c][32 p-pairs]
    __shared__ uint32_t at[64 * 34];   // bf16 pairs [64k][32 p-pairs]
    __shared__ float cmb[2][64][16];   // parity combine
    __shared__ float asum_l[64];

    int tid = threadIdx.x, bx = blockIdx.x;
    int n = bx >> 4, cb = (bx & 15) << 5;
    int l = tid & 63, w = tid >> 6;
    int kh = w & 1, ps = w >> 1;
    int h = l >> 5, cl = l & 31;

    if (tid < 64) asum_l[tid] = asum[n * 64 + tid];

    int xr = tid >> 3;                 // c-row (8 thr/row)
    int xq = (tid & 7) << 2;           // p quad (covers 0..31; +32 second)
    int ak = tid >> 2;                 // k-row (4 thr/row: 128B)
    int aj = (tid & 3) << 4;           // short col 0,16,32,48

    const float* xg = x + (size_t)n * 524288 + (size_t)(cb + xr) * 1024 + xq;
    const unsigned short* ag = aT + (size_t)n * 65536 + (size_t)ak * 1024 + aj;

    f32x16 acc;
#pragma unroll
    for (int r = 0; r < 16; ++r) acc[r] = 0.f;

    float4 pxa = *(const float4*)xg;
    float4 pxb = *(const float4*)(xg + 32);
    u32x4 pa0 = *(const u32x4*)ag;
    u32x4 pa1 = *(const u32x4*)(ag + 8);

    for (int ch = 0; ch < 16; ++ch) {
        __syncthreads();
        int xb = xr * 34 + (xq >> 1);
        *(uint2*)&xt[xb] = make_uint2(packbf(pxa.x, pxa.y), packbf(pxa.z, pxa.w));
        *(uint2*)&xt[xb + 16] = make_uint2(packbf(pxb.x, pxb.y), packbf(pxb.z, pxb.w));
        int ab = ak * 34 + (aj >> 1);
        *(uint2*)&at[ab] = make_uint2(pa0[0], pa0[1]);
        *(uint2*)&at[ab + 2] = make_uint2(pa0[2], pa0[3]);
        *(uint2*)&at[ab + 4] = make_uint2(pa1[0], pa1[1]);
        *(uint2*)&at[ab + 6] = make_uint2(pa1[2], pa1[3]);
        __syncthreads();
        if (ch < 15) {
            int p0 = (ch + 1) << 6;
            pxa = *(const float4*)(xg + p0);
            pxb = *(const float4*)(xg + p0 + 32);
            pa0 = *(const u32x4*)(ag + p0);
            pa1 = *(const u32x4*)(ag + p0 + 8);
        }
        if (ps == (ch & 1)) {  // wave-uniform parity split
#pragma unroll
            for (int s = 0; s < 4; ++s) {
                int va = (32 * kh + cl) * 34 + 8 * s + 4 * h;
                uint2 f0 = *(const uint2*)&at[va];
                uint2 f1 = *(const uint2*)&at[va + 2];
                int vb = cl * 34 + 8 * s + 4 * h;
                uint2 g0 = *(const uint2*)&xt[vb];
                uint2 g1 = *(const uint2*)&xt[vb + 2];
                u32x4 afp, bfp;
                afp[0] = f0.x; afp[1] = f0.y; afp[2] = f1.x; afp[3] = f1.y;
                bfp[0] = g0.x; bfp[1] = g0.y; bfp[2] = g1.x; bfp[3] = g1.y;
                acc = __builtin_amdgcn_mfma_f32_32x32x16_bf16(
                    __builtin_bit_cast(bf16x8, afp),
                    __builtin_bit_cast(bf16x8, bfp), acc, 0, 0, 0);
            }
        }
    }
    __syncthreads();
    if (ps == 1) {
#pragma unroll
        for (int r = 0; r < 16; ++r) cmb[kh][l][r] = acc[r];
    }
    __syncthreads();
    if (ps == 0) {
#pragma unroll
        for (int r = 0; r < 16; ++r) {
            int k = (r & 3) + 8 * (r >> 2) + 4 * h + 32 * kh;
            int c = cb + cl;
            float val = acc[r] + cmb[kh][l][r];
            val = fmaf(-asum_l[k], vocabs[k * 512 + c], val);
            out[(size_t)n * 32768 + (size_t)k * 512 + c] = val;
            float t2 = val * val;
#pragma unroll
            for (int off = 1; off <= 16; off <<= 1) t2 += __shfl_xor(t2, off, 64);
            if (cl == 0) atomicAdd(&knorm[n * 64 + k], t2);
        }
    }
}

// ---------------- scale: intra-norm (per k) * global norm (per n), in place -
__global__ __launch_bounds__(256) void scale_kernel(float* __restrict__ out,
                                                    const float* __restrict__ knorm) {
    int n = blockIdx.y;
    int sb = blockIdx.x;
    int tid = threadIdx.x;
    __shared__ float sc[64];
    __shared__ float tots;
    if (tid < 64) {
        float kn = knorm[n * 64 + tid];
        float nk = sqrtf(kn);
        float inv = 1.0f / fmaxf(nk, EPSN);
        sc[tid] = inv;
        float t = nk * inv;
        float t2 = t * t;
#pragma unroll
        for (int off = 32; off > 0; off >>= 1) t2 += __shfl_xor(t2, off, 64);
        if (tid == 0) tots = t2;
    }
    __syncthreads();
    float invt = 1.0f / fmaxf(sqrtf(tots), EPSN);
    float* base = out + (size_t)n * 32768 + sb * 4096;
#pragma unroll
    for (int i = 0; i < 16; ++i) {
        int idx = tid + 256 * i;
        int k = (sb * 4096 + idx) >> 9;
        base[idx] *= sc[k] * invt;
    }
}

extern "C" void kernel_launch(void* const* d_in, const int* in_sizes, int n_in,
                              void* d_out, int out_size, void* d_ws, size_t ws_size,
                              hipStream_t stream) {
    const float* x = (const float*)d_in[0];       // [32,512,32,32]
    const float* vocabs = (const float*)d_in[1];  // [64,512]
    float* out = (float*)d_out;                   // [32, 32768]
    char* ws = (char*)d_ws;
    unsigned short* vh = (unsigned short*)(ws);            // 65536 B
    unsigned short* vl = (unsigned short*)(ws + 65536);    // 65536 B
    float* bias  = (float*)(ws + 131072);                  //   256 B
    float* asum  = (float*)(ws + 131328);                  //  8192 B
    float* knorm = (float*)(ws + 139520);                  //  8192 B
    unsigned short* aT = (unsigned short*)(ws + 147712);   // 4 MB : a2 [n][k][p]

    prep_kernel<<<64, 64, 0, stream>>>(vocabs, vh, vl, bias, asum);  // zeroes asum+knorm
    assign_kernel<<<512, 256, 0, stream>>>(x, vh, vl, bias, aT, asum);
    vlad_kernel<<<512, 256, 0, stream>>>(x, aT, asum, vocabs, out, knorm);
    scale_kernel<<<dim3(8, 32), 256, 0, stream>>>(out, knorm);
}